// Round 1
// baseline (286.631 us; speedup 1.0000x reference)
//
#include <hip/hip_runtime.h>

// ---------------------------------------------------------------------------
// PAM module: conv3x3s2 -> qkv -> flash attention (bf16 MFMA) -> gamma ->
// bilinear upsample (align_corners) + residual.
// Shapes: x[8][64][128][128] f32, pooled h=w=64 -> N=4096, d_qk=32, d_v=64.
// ---------------------------------------------------------------------------

typedef __attribute__((ext_vector_type(8))) short bf16x8;   // 8 bf16 (4 VGPRs)
typedef __attribute__((ext_vector_type(4))) float f32x4;

#define DEV static __device__ __forceinline__

DEV unsigned f2bf(float f) {                  // RNE f32 -> bf16 bits
  union { float f; unsigned u; } a; a.f = f;
  return (a.u + 0x7FFFu + ((a.u >> 16) & 1u)) >> 16;
}
DEV unsigned pack2bf(float lo, float hi) { return f2bf(lo) | (f2bf(hi) << 16); }
DEV bf16x8 mk_bf16x8(unsigned w0, unsigned w1, unsigned w2, unsigned w3) {
  union { unsigned u[4]; bf16x8 v; } x;
  x.u[0] = w0; x.u[1] = w1; x.u[2] = w2; x.u[3] = w3;
  return x.v;
}

// ---------------------------------------------------------------------------
// Kernel 1: 3x3 stride-2 pad-1 conv, fp32.  grid = (B=8)*(oy=64) blocks, 256 thr.
// Each block: one output row oy, all 64 ox, all 64 oc. Thread: 4 oc x 4 ox.
// ---------------------------------------------------------------------------
#define ICC 16
__global__ __launch_bounds__(256) void conv3x3s2_kernel(
    const float* __restrict__ x, const float* __restrict__ w,
    const float* __restrict__ bias, float* __restrict__ xp) {
  const int bid = blockIdx.x;
  const int b = bid >> 6;
  const int oy = bid & 63;
  const int t = threadIdx.x;
  __shared__ float sIn[ICC][3][130];    // [ic][ky][ix+1], zero-padded ends
  __shared__ float sW[ICC][64][9];      // [ic][oc][k]
  const int ox0 = (t & 15) << 2;
  const int oc0 = (t >> 4) << 2;
  float acc[4][4];
  #pragma unroll
  for (int i = 0; i < 4; ++i)
    #pragma unroll
    for (int j = 0; j < 4; ++j) acc[i][j] = 0.f;

  for (int icb = 0; icb < 64; icb += ICC) {
    // stage input rows (3 rows x 130 cols x ICC channels), zero at pads
    for (int idx = t; idx < ICC * 3 * 130; idx += 256) {
      int ic = idx / 390; int rem = idx - ic * 390;
      int ky = rem / 130; int xi = rem - ky * 130;
      int iy = 2 * oy + ky - 1;
      int ix = xi - 1;
      float v = 0.f;
      if (iy >= 0 && iy < 128 && ix >= 0 && ix < 128)
        v = x[((size_t)((b * 64 + icb + ic) * 128 + iy)) * 128 + ix];
      sIn[ic][ky][xi] = v;
    }
    // stage weight chunk, coalesced in (ic,k) per oc
    for (int idx = t; idx < ICC * 64 * 9; idx += 256) {
      int oc = idx / (ICC * 9); int rem = idx - oc * (ICC * 9);
      int ic = rem / 9; int k = rem - ic * 9;
      sW[ic][oc][k] = w[(size_t)(oc * 64 + icb + ic) * 9 + k];
    }
    __syncthreads();
    for (int ic = 0; ic < ICC; ++ic) {
      float wr[4][9];
      #pragma unroll
      for (int i = 0; i < 4; ++i)
        #pragma unroll
        for (int k = 0; k < 9; ++k) wr[i][k] = sW[ic][oc0 + i][k];
      float in[3][9];
      #pragma unroll
      for (int ky = 0; ky < 3; ++ky)
        #pragma unroll
        for (int d = 0; d < 9; ++d) in[ky][d] = sIn[ic][ky][2 * ox0 + d];
      #pragma unroll
      for (int i = 0; i < 4; ++i)
        #pragma unroll
        for (int j = 0; j < 4; ++j) {
          float s = acc[i][j];
          #pragma unroll
          for (int ky = 0; ky < 3; ++ky)
            #pragma unroll
            for (int kx = 0; kx < 3; ++kx)
              s += wr[i][ky * 3 + kx] * in[ky][2 * j + kx];
          acc[i][j] = s;
        }
    }
    __syncthreads();
  }
  #pragma unroll
  for (int i = 0; i < 4; ++i) {
    float bb = bias[oc0 + i];
    f32x4 vv = {acc[i][0] + bb, acc[i][1] + bb, acc[i][2] + bb, acc[i][3] + bb};
    *reinterpret_cast<f32x4*>(
        &xp[((size_t)((b * 64 + oc0 + i) * 64 + oy)) * 64 + ox0]) = vv;
  }
}

// ---------------------------------------------------------------------------
// Kernel 2: q/k/v 1x1 convs.  q,k stored transposed [B][N][32] bf16 (row per
// position, channel-contiguous); v stored [B][64][N] bf16.
// grid = 256 blocks (8 b x 32 n-blocks of 128), 256 thr: t<128 -> q+k, else v.
// ---------------------------------------------------------------------------
__global__ __launch_bounds__(256) void qkv_kernel(
    const float* __restrict__ xp,
    const float* __restrict__ qw, const float* __restrict__ qbias,
    const float* __restrict__ kw, const float* __restrict__ kbias,
    const float* __restrict__ vw, const float* __restrict__ vbias,
    unsigned short* __restrict__ qT, unsigned short* __restrict__ kT,
    unsigned short* __restrict__ vM) {
  __shared__ float s_q[2048], s_k[2048], s_v[4096];
  __shared__ float s_qb[32], s_kb[32], s_vb[64];
  const int t = threadIdx.x;
  for (int i = t; i < 2048; i += 256) { s_q[i] = qw[i]; s_k[i] = kw[i]; }
  for (int i = t; i < 4096; i += 256) s_v[i] = vw[i];
  if (t < 32) { s_qb[t] = qbias[t]; s_kb[t] = kbias[t]; }
  else if (t < 96) s_vb[t - 32] = vbias[t - 32];
  __syncthreads();

  const int b = blockIdx.x >> 5;
  const int nbase = (blockIdx.x & 31) << 7;
  const bool roleA = t < 128;
  const int n = nbase + (roleA ? t : t - 128);

  float xin[64];
  const float* xpp = xp + ((size_t)(b << 6) << 12) + n;
  #pragma unroll
  for (int c = 0; c < 64; ++c) xin[c] = xpp[(size_t)c << 12];

  if (roleA) {
    unsigned* qdst = reinterpret_cast<unsigned*>(qT + (((size_t)(b << 12) + n) << 5));
    unsigned* kdst = reinterpret_cast<unsigned*>(kT + (((size_t)(b << 12) + n) << 5));
    for (int o2 = 0; o2 < 16; ++o2) {
      float aq0 = s_qb[2 * o2], aq1 = s_qb[2 * o2 + 1];
      float ak0 = s_kb[2 * o2], ak1 = s_kb[2 * o2 + 1];
      const float* wq0 = &s_q[(2 * o2) * 64];
      const float* wk0 = &s_k[(2 * o2) * 64];
      #pragma unroll
      for (int c = 0; c < 64; ++c) {
        const float xv = xin[c];
        aq0 += wq0[c] * xv;       aq1 += wq0[64 + c] * xv;
        ak0 += wk0[c] * xv;       ak1 += wk0[64 + c] * xv;
      }
      qdst[o2] = pack2bf(aq0, aq1);
      kdst[o2] = pack2bf(ak0, ak1);
    }
  } else {
    for (int o = 0; o < 64; ++o) {
      float av = s_vb[o];
      const float* wv = &s_v[o * 64];
      #pragma unroll
      for (int c = 0; c < 64; ++c) av += wv[c] * xin[c];
      vM[(((size_t)(b << 6) + o) << 12) + n] = (unsigned short)f2bf(av);
    }
  }
}

// ---------------------------------------------------------------------------
// Kernel 3: flash attention, bf16 MFMA 16x16x32.
// One wave = 32 query rows (2 n-tiles of 16) of one batch. 1024 waves total.
// Swapped QK^T: S^T = mfma(A=K-tile, B=Q-tile) so softmax reduce = shfl 16,32.
// Layout facts used (guide-verified / standard gfx9):
//   A: lane holds A[lane%16][8*(lane/16)+i];  B: B[8*(lane/16)+i][lane%16]
//   D: lane holds D[4*(lane/16)+r][lane%16]
// ---------------------------------------------------------------------------
__global__ __launch_bounds__(256) void attn_kernel(
    const unsigned short* __restrict__ qT, const unsigned short* __restrict__ kT,
    const unsigned short* __restrict__ vM, const float* __restrict__ gamma_p,
    float* __restrict__ attn_out) {
  const int t = threadIdx.x;
  const int wid = blockIdx.x * 4 + (t >> 6);
  const int b = wid >> 7;              // 128 wave-tiles per batch
  const int n0 = (wid & 127) << 5;     // 32 queries per wave
  const int lane = t & 63;
  const int lr = lane & 15;
  const int lg = lane >> 4;

  const unsigned short* qp = qT + (((size_t)(b << 12) + n0 + lr) << 5) + (lg << 3);
  bf16x8 bq0 = *reinterpret_cast<const bf16x8*>(qp);
  bf16x8 bq1 = *reinterpret_cast<const bf16x8*>(qp + (16 << 5));

  const unsigned short* kbase = kT + ((size_t)(b << 12) << 5) + (lr << 5) + (lg << 3);
  const unsigned short* vbase = vM + ((size_t)((b << 6) + lr) << 12) + (lg << 3);

  f32x4 acc[2][4];
  #pragma unroll
  for (int i = 0; i < 2; ++i)
    #pragma unroll
    for (int j = 0; j < 4; ++j) acc[i][j] = (f32x4){0.f, 0.f, 0.f, 0.f};
  float m_run[2] = {-1e30f, -1e30f};
  float l_run[2] = {0.f, 0.f};

  bf16x8 ka[4];
  #pragma unroll
  for (int j = 0; j < 4; ++j)
    ka[j] = *reinterpret_cast<const bf16x8*>(kbase + ((size_t)(16 * j) << 5));

  const int s0 = lr + ((lane & 16) << 1);   // lr + 32*(lg&1)
  const int s1 = s0 + 16;
  const bool hi = (lane & 32) != 0;         // lg >> 1

  for (int km = 0; km < 4096; km += 64) {
    // prefetch V for this chunk, K for next chunk
    bf16x8 va[2][4];
    #pragma unroll
    for (int h = 0; h < 2; ++h)
      #pragma unroll
      for (int ct = 0; ct < 4; ++ct)
        va[h][ct] = *reinterpret_cast<const bf16x8*>(
            vbase + ((size_t)(ct << 4) << 12) + km + (h << 5));
    const int kmn = (km + 64) & 4095;
    bf16x8 kn[4];
    #pragma unroll
    for (int j = 0; j < 4; ++j)
      kn[j] = *reinterpret_cast<const bf16x8*>(kbase + ((size_t)(kmn + 16 * j) << 5));

    // S^T tiles: rows = keys, cols = queries
    f32x4 st[2][4];
    const f32x4 z4 = {0.f, 0.f, 0.f, 0.f};
    #pragma unroll
    for (int j = 0; j < 4; ++j) {
      st[0][j] = __builtin_amdgcn_mfma_f32_16x16x32_bf16(ka[j], bq0, z4, 0, 0, 0);
      st[1][j] = __builtin_amdgcn_mfma_f32_16x16x32_bf16(ka[j], bq1, z4, 0, 0, 0);
    }

    unsigned pw[2][4][2];
    #pragma unroll
    for (int nt = 0; nt < 2; ++nt) {
      float cm = st[nt][0][0];
      #pragma unroll
      for (int j = 0; j < 4; ++j)
        #pragma unroll
        for (int r = 0; r < 4; ++r) cm = fmaxf(cm, st[nt][j][r]);
      cm = fmaxf(cm, __shfl_xor(cm, 16, 64));
      cm = fmaxf(cm, __shfl_xor(cm, 32, 64));
      const float mnew = fmaxf(m_run[nt], cm);
      const float sc = __expf(m_run[nt] - mnew);
      m_run[nt] = mnew;
      float ps = 0.f;
      #pragma unroll
      for (int j = 0; j < 4; ++j) {
        float p0 = __expf(st[nt][j][0] - mnew);
        float p1 = __expf(st[nt][j][1] - mnew);
        float p2 = __expf(st[nt][j][2] - mnew);
        float p3 = __expf(st[nt][j][3] - mnew);
        ps += (p0 + p1) + (p2 + p3);
        pw[nt][j][0] = pack2bf(p0, p1);
        pw[nt][j][1] = pack2bf(p2, p3);
      }
      ps += __shfl_xor(ps, 16, 64);
      ps += __shfl_xor(ps, 32, 64);
      l_run[nt] = l_run[nt] * sc + ps;
      #pragma unroll
      for (int ct = 0; ct < 4; ++ct) acc[nt][ct] *= sc;
    }

    // PV: redistribute P^T (D-layout) into B-operand layout via shuffles
    #pragma unroll
    for (int h = 0; h < 2; ++h) {
      #pragma unroll
      for (int nt = 0; nt < 2; ++nt) {
        const int f0 = 2 * h, f1 = 2 * h + 1;
        unsigned a0 = __shfl((int)pw[nt][f0][0], s0, 64);
        unsigned a1 = __shfl((int)pw[nt][f0][1], s0, 64);
        unsigned a2 = __shfl((int)pw[nt][f0][0], s1, 64);
        unsigned a3 = __shfl((int)pw[nt][f0][1], s1, 64);
        unsigned c0 = __shfl((int)pw[nt][f1][0], s0, 64);
        unsigned c1 = __shfl((int)pw[nt][f1][1], s0, 64);
        unsigned c2 = __shfl((int)pw[nt][f1][0], s1, 64);
        unsigned c3 = __shfl((int)pw[nt][f1][1], s1, 64);
        bf16x8 pb = mk_bf16x8(hi ? c0 : a0, hi ? c1 : a1, hi ? c2 : a2, hi ? c3 : a3);
        #pragma unroll
        for (int ct = 0; ct < 4; ++ct)
          acc[nt][ct] = __builtin_amdgcn_mfma_f32_16x16x32_bf16(va[h][ct], pb,
                                                                acc[nt][ct], 0, 0, 0);
      }
    }
    #pragma unroll
    for (int j = 0; j < 4; ++j) ka[j] = kn[j];
  }

  const float g = gamma_p[0];
  #pragma unroll
  for (int nt = 0; nt < 2; ++nt) {
    const float s = g / l_run[nt];
    const int ncol = n0 + (nt << 4) + lr;
    #pragma unroll
    for (int ct = 0; ct < 4; ++ct)
      #pragma unroll
      for (int r = 0; r < 4; ++r) {
        const int c = (ct << 4) + (lg << 2) + r;
        attn_out[((size_t)((b << 6) + c) << 12) + ncol] = acc[nt][ct][r] * s;
      }
  }
}

// ---------------------------------------------------------------------------
// Kernel 4: bilinear upsample 64->128 (align_corners=True) + residual add.
// Thread: 4 consecutive X. grid = 8192 blocks x 256.
// ---------------------------------------------------------------------------
__global__ __launch_bounds__(256) void upsample_residual_kernel(
    const float* __restrict__ attn_out, const float* __restrict__ x,
    float* __restrict__ out) {
  const int idx = blockIdx.x * 256 + threadIdx.x;   // 2^21 total
  const int X0 = (idx & 31) << 2;
  int rem = idx >> 5;
  const int Y = rem & 127; rem >>= 7;
  const int c = rem & 63;
  const int b = rem >> 6;

  const float sr = 63.0f / 127.0f;
  float fy = Y * sr;
  int iy = (int)fy; if (iy > 62) iy = 62;
  const float ty = fy - (float)iy;
  const float* ap = attn_out + (((size_t)(b * 64 + c)) << 12);
  const float* r0 = ap + iy * 64;
  const float* r1 = r0 + 64;

  float tmp[4];
  #pragma unroll
  for (int k = 0; k < 4; ++k) {
    const int X = X0 + k;
    float fx = X * sr;
    int ix = (int)fx; if (ix > 62) ix = 62;
    const float tx = fx - (float)ix;
    float v0 = r0[ix] + tx * (r0[ix + 1] - r0[ix]);
    float v1 = r1[ix] + tx * (r1[ix + 1] - r1[ix]);
    tmp[k] = v0 + ty * (v1 - v0);
  }
  const size_t o = (((size_t)((b * 64 + c) * 128 + Y)) << 7) + X0;
  f32x4 xv = *reinterpret_cast<const f32x4*>(x + o);
  f32x4 ov = {tmp[0] + xv[0], tmp[1] + xv[1], tmp[2] + xv[2], tmp[3] + xv[3]};
  *reinterpret_cast<f32x4*>(out + o) = ov;
}

// ---------------------------------------------------------------------------
extern "C" void kernel_launch(void* const* d_in, const int* in_sizes, int n_in,
                              void* d_out, int out_size, void* d_ws, size_t ws_size,
                              hipStream_t stream) {
  const float* x      = (const float*)d_in[0];
  const float* pool_w = (const float*)d_in[1];
  const float* pool_b = (const float*)d_in[2];
  const float* q_w    = (const float*)d_in[3];
  const float* q_b    = (const float*)d_in[4];
  const float* k_w    = (const float*)d_in[5];
  const float* k_b    = (const float*)d_in[6];
  const float* v_w    = (const float*)d_in[7];
  const float* v_b    = (const float*)d_in[8];
  const float* gamma  = (const float*)d_in[9];
  float* out = (float*)d_out;

  char* ws = (char*)d_ws;
  float* xp            = (float*)(ws);                      // 8*64*4096*4  = 8 MiB
  unsigned short* qT   = (unsigned short*)(ws + 8388608);   // 8*4096*32*2  = 2 MiB
  unsigned short* kT   = (unsigned short*)(ws + 10485760);  // 2 MiB
  unsigned short* vM   = (unsigned short*)(ws + 12582912);  // 8*64*4096*2  = 4 MiB
  float* attn_out      = (float*)(ws + 16777216);           // 8 MiB

  conv3x3s2_kernel<<<512, 256, 0, stream>>>(x, pool_w, pool_b, xp);
  qkv_kernel<<<256, 256, 0, stream>>>(xp, q_w, q_b, k_w, k_b, v_w, v_b, qT, kT, vM);
  attn_kernel<<<256, 256, 0, stream>>>(qT, kT, vM, gamma, attn_out);
  upsample_residual_kernel<<<8192, 256, 0, stream>>>(attn_out, x, out);
}

// Round 2
// 119.066 us; speedup vs baseline: 2.4073x; 2.4073x over previous
//
#include <hip/hip_runtime.h>

// ---------------------------------------------------------------------------
// PAM module: [prep weights] -> fused conv3x3s2+qkv (bf16 MFMA implicit GEMM)
// -> flash attention w/ in-block KV-split x4 -> bilinear upsample + residual.
// Shapes: x[8][64][128][128] f32, pooled h=w=64 -> N=4096, d_qk=32, d_v=64.
// ---------------------------------------------------------------------------

typedef __attribute__((ext_vector_type(8))) short bf16x8;   // 8 bf16 (4 VGPRs)
typedef __attribute__((ext_vector_type(4))) float f32x4;

#define DEV static __device__ __forceinline__

DEV unsigned f2bf(float f) {                  // RNE f32 -> bf16 bits
  union { float f; unsigned u; } a; a.f = f;
  return (a.u + 0x7FFFu + ((a.u >> 16) & 1u)) >> 16;
}
DEV unsigned cvtpk(float lo, float hi) {      // v_cvt_pk_bf16_f32 (RNE, 1 instr)
  unsigned r;
  asm("v_cvt_pk_bf16_f32 %0, %1, %2" : "=v"(r) : "v"(lo), "v"(hi));
  return r;
}
DEV bf16x8 mk_bf16x8(unsigned w0, unsigned w1, unsigned w2, unsigned w3) {
  union { unsigned u[4]; bf16x8 v; } x;
  x.u[0] = w0; x.u[1] = w1; x.u[2] = w2; x.u[3] = w3;
  return x.v;
}

// ---------------------------------------------------------------------------
// Kernel 0: weight prep.  Ag[oc][k=tap*64+ic] bf16 (conv A-operand, row-major
// K=576); A2g[row][ic] bf16 (rows 0-31 q_w, 32-63 k_w, 64-127 v_w);
// bias2[128] f32 (q_b,k_b,v_b concat).
// ---------------------------------------------------------------------------
__global__ __launch_bounds__(256) void prep_kernel(
    const float* __restrict__ pw, const float* __restrict__ qw,
    const float* __restrict__ kw, const float* __restrict__ vw,
    const float* __restrict__ qb, const float* __restrict__ kb,
    const float* __restrict__ vb,
    unsigned short* __restrict__ Ag, unsigned short* __restrict__ A2g,
    float* __restrict__ bias2) {
  const int i = blockIdx.x * 256 + threadIdx.x;
  if (i < 36864) {
    const int oc = i / 576, k = i - oc * 576;
    const int tap = k >> 6, ic = k & 63;
    Ag[i] = (unsigned short)f2bf(pw[(oc * 64 + ic) * 9 + tap]);
  }
  const int j = i - 36864;
  if (j >= 0 && j < 8192) {
    const int r = j >> 6, c = j & 63;
    const float* src = r < 32 ? qw + r * 64 : (r < 64 ? kw + (r - 32) * 64
                                                      : vw + (r - 64) * 64);
    A2g[j] = (unsigned short)f2bf(src[c]);
  }
  if (j >= 8192 && j < 8320) {
    const int r = j - 8192;
    bias2[r] = r < 32 ? qb[r] : (r < 64 ? kb[r - 32] : vb[r - 64]);
  }
}

// ---------------------------------------------------------------------------
// Kernel 1: fused conv3x3s2 + qkv, bf16 MFMA 16x16x32.
// Block = (b, oy): 64 output positions x 64 oc, then qkv GEMM on the tile.
// sIn: bf16 [pos=ky*130+xi][ic=64], octet-XOR swizzled (T2) so B-frags are
// one conflict-free ds_read_b128.  k-order: k = tap*64 + ic.
// ---------------------------------------------------------------------------
__global__ __launch_bounds__(256) void convqkv_kernel(
    const float* __restrict__ x, const unsigned short* __restrict__ Ag,
    const float* __restrict__ pool_b, const unsigned short* __restrict__ A2g,
    const float* __restrict__ bias2,
    unsigned short* __restrict__ qT, unsigned short* __restrict__ kT,
    unsigned short* __restrict__ vM) {
  const int b = blockIdx.x >> 6, oy = blockIdx.x & 63;
  const int t = threadIdx.x, w = t >> 6, lane = t & 63;
  const int lr = lane & 15, lg = lane >> 4;
  __shared__ unsigned short sIn[390 * 64];   // 48.75 KB, swizzled bytes
  __shared__ unsigned short sXP[64 * 64];    // 8 KB, swizzled bytes
  char* sInB = (char*)sIn;
  char* sXPB = (char*)sXP;

  // conv A-fragments: wave w owns oc block [w*16, w*16+16)
  bf16x8 af[18];
  {
    const unsigned short* ap = Ag + (w * 16 + lr) * 576 + (lg << 3);
    #pragma unroll
    for (int kc = 0; kc < 18; ++kc)
      af[kc] = *(const bf16x8*)(ap + kc * 32);
  }

  // stage input: pos = ky*130 + xi; iy = 2*oy+ky-1, ix = xi-1; zero pads.
  #pragma unroll
  for (int rr = 0; rr < 2; ++rr) {
    const int pos = t + rr * 256;
    if (pos < 390) {
      const int ky = pos / 130, xi = pos - ky * 130;
      const int iy = 2 * oy + ky - 1, ix = xi - 1;
      const bool ok = (iy >= 0) & (iy < 128) & (ix >= 0) & (ix < 128);
      const float* xs = x + ((size_t)(b * 64) * 128 + (ok ? iy : 0)) * 128 +
                        (ok ? ix : 0);
      const int sw = pos & 7;
      #pragma unroll
      for (int o = 0; o < 8; ++o) {
        float f[8];
        #pragma unroll
        for (int jj = 0; jj < 8; ++jj)
          f[jj] = ok ? xs[(size_t)(o * 8 + jj) * 16384] : 0.f;
        bf16x8 v = mk_bf16x8(cvtpk(f[0], f[1]), cvtpk(f[2], f[3]),
                             cvtpk(f[4], f[5]), cvtpk(f[6], f[7]));
        *(bf16x8*)(sInB + pos * 128 + ((o ^ sw) << 4)) = v;
      }
    }
  }
  __syncthreads();

  // conv GEMM: acc[nt] (nt = 16-col tile of positions)
  f32x4 acc[4];
  #pragma unroll
  for (int nt = 0; nt < 4; ++nt) acc[nt] = (f32x4){0.f, 0.f, 0.f, 0.f};
  #pragma unroll
  for (int kc = 0; kc < 18; ++kc) {
    const int tap = kc >> 1, ky = tap / 3, kx = tap - ky * 3;
    const int o = ((kc & 1) << 2) + lg;
    #pragma unroll
    for (int nt = 0; nt < 4; ++nt) {
      const int xi = 2 * (nt * 16 + lr) + kx;
      const int pos = ky * 130 + xi;
      bf16x8 bfr = *(const bf16x8*)(sInB + pos * 128 + ((o ^ (pos & 7)) << 4));
      acc[nt] = __builtin_amdgcn_mfma_f32_16x16x32_bf16(af[kc], bfr, acc[nt],
                                                        0, 0, 0);
    }
  }

  // + pool bias, pack to sXP (bf16, [pos][oc] oc-innermost, swizzled)
  const int ocBase = w * 16 + (lg << 2);
  float pb[4];
  #pragma unroll
  for (int r = 0; r < 4; ++r) pb[r] = pool_b[ocBase + r];
  const int ocOct = ocBase >> 3;
  const int withinB = (ocBase & 7) * 2;
  #pragma unroll
  for (int nt = 0; nt < 4; ++nt) {
    const int pos = nt * 16 + lr;
    const unsigned p01 = cvtpk(acc[nt][0] + pb[0], acc[nt][1] + pb[1]);
    const unsigned p23 = cvtpk(acc[nt][2] + pb[2], acc[nt][3] + pb[3]);
    char* base = sXPB + pos * 128 + ((ocOct ^ (pos & 7)) << 4) + withinB;
    *(unsigned*)(base) = p01;
    *(unsigned*)(base + 4) = p23;
  }
  __syncthreads();

  // qkv GEMM: A2 rows = [q(32); k(32); v(64)], K = 64 channels, N = 64 pos.
  bf16x8 a2[2][2];
  #pragma unroll
  for (int mt = 0; mt < 2; ++mt)
    #pragma unroll
    for (int kc2 = 0; kc2 < 2; ++kc2)
      a2[mt][kc2] = *(const bf16x8*)(A2g + ((2 * w + mt) * 16 + lr) * 64 +
                                     kc2 * 32 + (lg << 3));
  f32x4 acc2[2][4];
  #pragma unroll
  for (int mt = 0; mt < 2; ++mt)
    #pragma unroll
    for (int nt = 0; nt < 4; ++nt) acc2[mt][nt] = (f32x4){0.f, 0.f, 0.f, 0.f};
  #pragma unroll
  for (int kc2 = 0; kc2 < 2; ++kc2) {
    const int o2 = (kc2 << 2) + lg;
    #pragma unroll
    for (int nt = 0; nt < 4; ++nt) {
      const int pos = nt * 16 + lr;
      bf16x8 bfr = *(const bf16x8*)(sXPB + pos * 128 + ((o2 ^ (pos & 7)) << 4));
      acc2[0][nt] = __builtin_amdgcn_mfma_f32_16x16x32_bf16(a2[0][kc2], bfr,
                                                            acc2[0][nt], 0, 0, 0);
      acc2[1][nt] = __builtin_amdgcn_mfma_f32_16x16x32_bf16(a2[1][kc2], bfr,
                                                            acc2[1][nt], 0, 0, 0);
    }
  }

  // epilogue: + bias2, store q/k (bf16 [b][n][32]) and v (bf16 [b][64][n])
  const int n0g = oy << 6;
  #pragma unroll
  for (int mt = 0; mt < 2; ++mt) {
    const int rowB = (2 * w + mt) * 16 + (lg << 2);
    float b2[4];
    #pragma unroll
    for (int r = 0; r < 4; ++r) b2[r] = bias2[rowB + r];
    if (rowB < 32) {
      #pragma unroll
      for (int nt = 0; nt < 4; ++nt) {
        const int n = n0g + nt * 16 + lr;
        unsigned* dst = (unsigned*)(qT + (((size_t)(b << 12) + n) << 5) + rowB);
        dst[0] = cvtpk(acc2[mt][nt][0] + b2[0], acc2[mt][nt][1] + b2[1]);
        dst[1] = cvtpk(acc2[mt][nt][2] + b2[2], acc2[mt][nt][3] + b2[3]);
      }
    } else if (rowB < 64) {
      #pragma unroll
      for (int nt = 0; nt < 4; ++nt) {
        const int n = n0g + nt * 16 + lr;
        unsigned* dst = (unsigned*)(kT + (((size_t)(b << 12) + n) << 5) + rowB - 32);
        dst[0] = cvtpk(acc2[mt][nt][0] + b2[0], acc2[mt][nt][1] + b2[1]);
        dst[1] = cvtpk(acc2[mt][nt][2] + b2[2], acc2[mt][nt][3] + b2[3]);
      }
    } else {
      const int cv = rowB - 64;
      #pragma unroll
      for (int nt = 0; nt < 4; ++nt) {
        const int n = n0g + nt * 16 + lr;
        #pragma unroll
        for (int r = 0; r < 4; ++r)
          vM[(((size_t)(b << 6) + cv + r) << 12) + n] =
              (unsigned short)f2bf(acc2[mt][nt][r] + b2[r]);
      }
    }
  }
}

// ---------------------------------------------------------------------------
// Kernel 2: flash attention, in-block KV-split x4.
// Block = (b, 32-query tile); wave w handles keys [w*1024, w*1024+1024).
// Partial (acc, m, l) merged in LDS (octet-XOR swizzled), final write has
// gamma/l normalization.  b = blockIdx&7 -> each XCD serves one batch (L2).
// ---------------------------------------------------------------------------
__global__ __launch_bounds__(256) void attn_kernel(
    const unsigned short* __restrict__ qT, const unsigned short* __restrict__ kT,
    const unsigned short* __restrict__ vM, const float* __restrict__ gamma_p,
    float* __restrict__ attn_out) {
  const int t = threadIdx.x;
  const int b = blockIdx.x & 7;
  const int u = blockIdx.x >> 3;            // 0..127 query tile
  const int n0 = u << 5;
  const int w = t >> 6;                     // KV split
  const int lane = t & 63, lr = lane & 15, lg = lane >> 4;
  __shared__ float sAcc[4 * 64 * 32];       // 32 KB, swizzled bytes
  __shared__ float sM[4][2][16], sL[4][2][16];
  char* sAB = (char*)sAcc;

  const unsigned short* qp = qT + (((size_t)(b << 12) + n0 + lr) << 5) + (lg << 3);
  const bf16x8 bq0 = *(const bf16x8*)(qp);
  const bf16x8 bq1 = *(const bf16x8*)(qp + (16 << 5));

  const int kvbase = w << 10;
  const unsigned short* kbase =
      kT + (((size_t)(b << 12) + kvbase + lr) << 5) + (lg << 3);
  const unsigned short* vbase =
      vM + (((size_t)(b << 6) + lr) << 12) + kvbase + (lg << 3);

  f32x4 acc[2][4];
  #pragma unroll
  for (int i = 0; i < 2; ++i)
    #pragma unroll
    for (int j = 0; j < 4; ++j) acc[i][j] = (f32x4){0.f, 0.f, 0.f, 0.f};
  float m_run[2] = {-1e30f, -1e30f};
  float l_run[2] = {0.f, 0.f};

  bf16x8 ka[4];
  #pragma unroll
  for (int j = 0; j < 4; ++j)
    ka[j] = *(const bf16x8*)(kbase + ((size_t)(16 * j) << 5));

  const int s0 = lr + ((lane & 16) << 1);   // lr + 32*(lg&1)
  const int s1 = s0 + 16;
  const bool hi = (lane & 32) != 0;

  for (int km = 0; km < 1024; km += 64) {
    bf16x8 va[2][4];
    #pragma unroll
    for (int h = 0; h < 2; ++h)
      #pragma unroll
      for (int ct = 0; ct < 4; ++ct)
        va[h][ct] = *(const bf16x8*)(
            vbase + ((size_t)(ct << 4) << 12) + km + (h << 5));
    const int kmn = (km + 64) & 1023;
    bf16x8 kn[4];
    #pragma unroll
    for (int j = 0; j < 4; ++j)
      kn[j] = *(const bf16x8*)(kbase + ((size_t)(kmn + 16 * j) << 5));

    f32x4 st[2][4];
    const f32x4 z4 = {0.f, 0.f, 0.f, 0.f};
    #pragma unroll
    for (int j = 0; j < 4; ++j) {
      st[0][j] = __builtin_amdgcn_mfma_f32_16x16x32_bf16(ka[j], bq0, z4, 0, 0, 0);
      st[1][j] = __builtin_amdgcn_mfma_f32_16x16x32_bf16(ka[j], bq1, z4, 0, 0, 0);
    }

    unsigned pw_[2][4][2];
    #pragma unroll
    for (int nt = 0; nt < 2; ++nt) {
      float cm = st[nt][0][0];
      #pragma unroll
      for (int j = 0; j < 4; ++j)
        #pragma unroll
        for (int r = 0; r < 4; ++r) cm = fmaxf(cm, st[nt][j][r]);
      cm = fmaxf(cm, __shfl_xor(cm, 16, 64));
      cm = fmaxf(cm, __shfl_xor(cm, 32, 64));
      // defer-max (T13): skip rescale when max growth <= 8
      if (!__all(cm <= m_run[nt] + 8.0f)) {
        const float mnew = fmaxf(m_run[nt], cm);
        const float sc = __expf(m_run[nt] - mnew);
        m_run[nt] = mnew;
        l_run[nt] *= sc;
        #pragma unroll
        for (int ct = 0; ct < 4; ++ct) acc[nt][ct] *= sc;
      }
      const float mm = m_run[nt];
      float ps = 0.f;
      #pragma unroll
      for (int j = 0; j < 4; ++j) {
        const float p0 = __expf(st[nt][j][0] - mm);
        const float p1 = __expf(st[nt][j][1] - mm);
        const float p2 = __expf(st[nt][j][2] - mm);
        const float p3 = __expf(st[nt][j][3] - mm);
        ps += (p0 + p1) + (p2 + p3);
        pw_[nt][j][0] = cvtpk(p0, p1);
        pw_[nt][j][1] = cvtpk(p2, p3);
      }
      ps += __shfl_xor(ps, 16, 64);
      ps += __shfl_xor(ps, 32, 64);
      l_run[nt] += ps;
    }

    // PV: redistribute P^T (D-layout) into B-operand layout via shuffles
    #pragma unroll
    for (int h = 0; h < 2; ++h) {
      #pragma unroll
      for (int nt = 0; nt < 2; ++nt) {
        const int f0 = 2 * h, f1 = 2 * h + 1;
        unsigned a0 = __shfl((int)pw_[nt][f0][0], s0, 64);
        unsigned a1 = __shfl((int)pw_[nt][f0][1], s0, 64);
        unsigned a2 = __shfl((int)pw_[nt][f0][0], s1, 64);
        unsigned a3 = __shfl((int)pw_[nt][f0][1], s1, 64);
        unsigned c0 = __shfl((int)pw_[nt][f1][0], s0, 64);
        unsigned c1 = __shfl((int)pw_[nt][f1][1], s0, 64);
        unsigned c2 = __shfl((int)pw_[nt][f1][0], s1, 64);
        unsigned c3 = __shfl((int)pw_[nt][f1][1], s1, 64);
        bf16x8 pb = mk_bf16x8(hi ? c0 : a0, hi ? c1 : a1, hi ? c2 : a2, hi ? c3 : a3);
        #pragma unroll
        for (int ct = 0; ct < 4; ++ct)
          acc[nt][ct] = __builtin_amdgcn_mfma_f32_16x16x32_bf16(va[h][ct], pb,
                                                                acc[nt][ct], 0, 0, 0);
      }
    }
    #pragma unroll
    for (int j = 0; j < 4; ++j) ka[j] = kn[j];
  }

  // write partials to LDS (swizzled: q-vector index XOR lane&7)
  #pragma unroll
  for (int nt = 0; nt < 2; ++nt)
    #pragma unroll
    for (int ct = 0; ct < 4; ++ct) {
      const int q = nt * 4 + ct;
      *(f32x4*)(sAB + (w << 13) + lane * 128 + ((q ^ (lane & 7)) << 4)) =
          acc[nt][ct];
    }
  if (lane < 16) {
    sM[w][0][lane] = m_run[0];
    sM[w][1][lane] = m_run[1];
    sL[w][0][lane] = l_run[0];
    sL[w][1][lane] = l_run[1];
  }
  __syncthreads();

  // combine 4 splits; thread handles q-vectors {2w, 2w+1} for its lane
  const float g = gamma_p[0];
  #pragma unroll
  for (int qq = 0; qq < 2; ++qq) {
    const int q = 2 * w + qq;
    const int nt = q >> 2, ct = q & 3;
    const float m0 = sM[0][nt][lr], m1 = sM[1][nt][lr];
    const float m2 = sM[2][nt][lr], m3 = sM[3][nt][lr];
    const float M = fmaxf(fmaxf(m0, m1), fmaxf(m2, m3));
    const float e0 = __expf(m0 - M), e1 = __expf(m1 - M);
    const float e2 = __expf(m2 - M), e3 = __expf(m3 - M);
    const float L = e0 * sL[0][nt][lr] + e1 * sL[1][nt][lr] +
                    e2 * sL[2][nt][lr] + e3 * sL[3][nt][lr];
    const int off = lane * 128 + ((q ^ (lane & 7)) << 4);
    const f32x4 A0 = *(const f32x4*)(sAB + off);
    const f32x4 A1 = *(const f32x4*)(sAB + 8192 + off);
    const f32x4 A2 = *(const f32x4*)(sAB + 16384 + off);
    const f32x4 A3 = *(const f32x4*)(sAB + 24576 + off);
    const float sc = g / L;
    const f32x4 o = ((A0 * e0 + A1 * e1) + (A2 * e2 + A3 * e3)) * sc;
    const int ncol = n0 + (nt << 4) + lr;
    float* dst = attn_out +
                 (((size_t)((b << 6) + (ct << 4) + (lg << 2))) << 12) + ncol;
    dst[0] = o[0];
    dst[4096] = o[1];
    dst[8192] = o[2];
    dst[12288] = o[3];
  }
}

// ---------------------------------------------------------------------------
// Kernel 3: bilinear upsample 64->128 (align_corners=True) + residual add.
// ---------------------------------------------------------------------------
__global__ __launch_bounds__(256) void upsample_residual_kernel(
    const float* __restrict__ attn_out, const float* __restrict__ x,
    float* __restrict__ out) {
  const int idx = blockIdx.x * 256 + threadIdx.x;   // 2^21 total
  const int X0 = (idx & 31) << 2;
  int rem = idx >> 5;
  const int Y = rem & 127; rem >>= 7;
  const int c = rem & 63;
  const int b = rem >> 6;

  const float sr = 63.0f / 127.0f;
  float fy = Y * sr;
  int iy = (int)fy; if (iy > 62) iy = 62;
  const float ty = fy - (float)iy;
  const float* ap = attn_out + (((size_t)(b * 64 + c)) << 12);
  const float* r0 = ap + iy * 64;
  const float* r1 = r0 + 64;

  float tmp[4];
  #pragma unroll
  for (int k = 0; k < 4; ++k) {
    const int X = X0 + k;
    float fx = X * sr;
    int ix = (int)fx; if (ix > 62) ix = 62;
    const float tx = fx - (float)ix;
    float v0 = r0[ix] + tx * (r0[ix + 1] - r0[ix]);
    float v1 = r1[ix] + tx * (r1[ix + 1] - r1[ix]);
    tmp[k] = v0 + ty * (v1 - v0);
  }
  const size_t o = (((size_t)((b * 64 + c) * 128 + Y)) << 7) + X0;
  f32x4 xv = *reinterpret_cast<const f32x4*>(x + o);
  f32x4 ov = {tmp[0] + xv[0], tmp[1] + xv[1], tmp[2] + xv[2], tmp[3] + xv[3]};
  *reinterpret_cast<f32x4*>(out + o) = ov;
}

// ---------------------------------------------------------------------------
extern "C" void kernel_launch(void* const* d_in, const int* in_sizes, int n_in,
                              void* d_out, int out_size, void* d_ws, size_t ws_size,
                              hipStream_t stream) {
  const float* x      = (const float*)d_in[0];
  const float* pool_w = (const float*)d_in[1];
  const float* pool_b = (const float*)d_in[2];
  const float* q_w    = (const float*)d_in[3];
  const float* q_b    = (const float*)d_in[4];
  const float* k_w    = (const float*)d_in[5];
  const float* k_b    = (const float*)d_in[6];
  const float* v_w    = (const float*)d_in[7];
  const float* v_b    = (const float*)d_in[8];
  const float* gamma  = (const float*)d_in[9];
  float* out = (float*)d_out;

  char* ws = (char*)d_ws;
  unsigned short* Ag   = (unsigned short*)(ws);             // 73,728 B
  unsigned short* A2g  = (unsigned short*)(ws + 81920);     // 16,384 B
  float* bias2         = (float*)(ws + 98304);              // 512 B
  unsigned short* qT   = (unsigned short*)(ws + 1048576);   // 2 MiB
  unsigned short* kT   = (unsigned short*)(ws + 3145728);   // 2 MiB
  unsigned short* vM   = (unsigned short*)(ws + 5242880);   // 4 MiB
  float* attn_out      = (float*)(ws + 9437184);            // 8 MiB

  prep_kernel<<<177, 256, 0, stream>>>(pool_w, q_w, k_w, v_w, q_b, k_b, v_b,
                                       Ag, A2g, bias2);
  convqkv_kernel<<<512, 256, 0, stream>>>(x, Ag, pool_b, A2g, bias2, qT, kT, vM);
  attn_kernel<<<1024, 256, 0, stream>>>(qT, kT, vM, gamma, attn_out);
  upsample_residual_kernel<<<8192, 256, 0, stream>>>(attn_out, x, out);
}